// Round 4
// baseline (469.862 us; speedup 1.0000x reference)
//
#include <hip/hip_runtime.h>
#include <stdint.h>

#define NN   100000
#define NE   1600000
#define NG   512
#define HID  128
#define NOUT 64
#define SCAN_B 1024
#define NB   ((NN + SCAN_B - 1) / SCAN_B)   // 98 scan blocks

typedef __bf16 bf16_t;
typedef bf16_t bf16x8 __attribute__((ext_vector_type(8)));
typedef float  f32x4  __attribute__((ext_vector_type(4)));
typedef unsigned int u32;
typedef unsigned short u16;

__device__ __forceinline__ u16 f2b(float f) {
    union { float f; u32 u; } v; v.f = f;
    u32 u = v.u + 0x7fffu + ((v.u >> 16) & 1u);   // RNE
    return (u16)(u >> 16);
}
__device__ __forceinline__ float blo(u32 u) {
    union { u32 u; float f; } v; v.u = u << 16; return v.f;
}
__device__ __forceinline__ float bhi(u32 u) {
    union { u32 u; float f; } v; v.u = u & 0xffff0000u; return v.f;
}

// ---------------- CSR build ----------------
__global__ void k_hist(const int* __restrict__ dst, int* __restrict__ cnt) {
    int i = blockIdx.x * blockDim.x + threadIdx.x;
    if (i < NE) atomicAdd(&cnt[dst[i]], 1);
}

__global__ void k_dinv(const int* __restrict__ cnt, const int* __restrict__ batch,
                       float* __restrict__ dinv, int* __restrict__ cntg) {
    int i = blockIdx.x * blockDim.x + threadIdx.x;
    if (i < NN) {
        dinv[i] = rsqrtf((float)(cnt[i] + 1));
        atomicAdd(&cntg[batch[i]], 1);
    }
}

__global__ __launch_bounds__(256) void k_scan1(const int* __restrict__ cnt,
                                               int* __restrict__ rp, int* __restrict__ bsum) {
    __shared__ int sh[256];
    int b = blockIdx.x, t = threadIdx.x;
    int base = b * SCAN_B + t * 4;
    int v[4]; int s = 0;
#pragma unroll
    for (int j = 0; j < 4; j++) { int idx = base + j; v[j] = (idx < NN) ? cnt[idx] : 0; s += v[j]; }
    sh[t] = s; __syncthreads();
    for (int off = 1; off < 256; off <<= 1) {
        int x = (t >= off) ? sh[t - off] : 0;
        __syncthreads();
        sh[t] += x;
        __syncthreads();
    }
    if (t == 255) bsum[b] = sh[255];
    int run = sh[t] - s;
#pragma unroll
    for (int j = 0; j < 4; j++) { int idx = base + j; if (idx < NN) rp[idx] = run; run += v[j]; }
}

__global__ __launch_bounds__(128) void k_scan2(const int* __restrict__ bsum,
                                               int* __restrict__ boff, int* __restrict__ rpN) {
    __shared__ int sh[128];
    int t = threadIdx.x;
    int v = (t < NB) ? bsum[t] : 0;
    sh[t] = v; __syncthreads();
    for (int off = 1; off < 128; off <<= 1) {
        int x = (t >= off) ? sh[t - off] : 0;
        __syncthreads();
        sh[t] += x;
        __syncthreads();
    }
    if (t < NB) boff[t] = sh[t] - v;
    if (t == 127) rpN[0] = sh[127];   // == NE
}

__global__ void k_scan3(int* __restrict__ rp, const int* __restrict__ boff) {
    int i = blockIdx.x * blockDim.x + threadIdx.x;
    if (i < NN) rp[i] += boff[i / SCAN_B];
}

__global__ void k_fill(const int* __restrict__ src, const int* __restrict__ dst,
                       const int* __restrict__ rp, int* __restrict__ cur, int* __restrict__ col) {
    int e = blockIdx.x * blockDim.x + threadIdx.x;
    if (e < NE) {
        int d = dst[e];
        int pos = rp[d] + atomicAdd(&cur[d], 1);
        col[pos] = src[e];
    }
}

// ---------------- weight pack (fragment order) ----------------
__global__ void k_pack(const float* __restrict__ W, u16* __restrict__ Wp) {
    int tid = blockIdx.x * blockDim.x + threadIdx.x;
    if (tid >= 32 * 64) return;
    int f = tid >> 6, l = tid & 63;
    int c = f >> 2, s = f & 3;
    int n  = c * 16 + (l & 15);
    int k0 = s * 32 + ((l >> 4) << 3);
#pragma unroll
    for (int j = 0; j < 8; j++) Wp[tid * 8 + j] = f2b(W[(k0 + j) * HID + n]);
}

// ---------------- GEMM: h = X @ W, out g = bf16(h * dinv[row]) ----------------
template<int INF32>
__global__ __launch_bounds__(256) void k_gemm(const void* __restrict__ Xin,
                                              const u16* __restrict__ Wp,
                                              const float* __restrict__ dinv,
                                              u16* __restrict__ Gout) {
    int w = threadIdx.x >> 6, l = threadIdx.x & 63;
    int r0  = blockIdx.x * 64 + w * 16;
    int l15 = l & 15, lh = l >> 4;
    int arow = r0 + l15;
    int arc  = (arow < NN) ? arow : (NN - 1);

    const float* Xf = (const float*)Xin;
    const u16*   Xh = (const u16*)Xin;

    f32x4 acc[8];
#pragma unroll
    for (int c = 0; c < 8; c++) acc[c] = (f32x4){0.f, 0.f, 0.f, 0.f};

#pragma unroll
    for (int s = 0; s < 4; s++) {
        int k0 = s * 32 + lh * 8;
        bf16x8 a;
        if (INF32) {
            f32x4 p0 = *(const f32x4*)(Xf + arc * HID + k0);
            f32x4 p1 = *(const f32x4*)(Xf + arc * HID + k0 + 4);
            union { bf16x8 v; u16 h[8]; } au;
#pragma unroll
            for (int j = 0; j < 4; j++) { au.h[j] = f2b(p0[j]); au.h[j + 4] = f2b(p1[j]); }
            a = au.v;
        } else {
            a = *(const bf16x8*)(Xh + arc * HID + k0);
        }
#pragma unroll
        for (int c = 0; c < 8; c++) {
            bf16x8 b = *(const bf16x8*)(Wp + ((c * 4 + s) * 64 + l) * 8);
            acc[c] = __builtin_amdgcn_mfma_f32_16x16x32_bf16(a, b, acc[c], 0, 0, 0);
        }
    }
#pragma unroll
    for (int q = 0; q < 4; q++) {
        int row = r0 + lh * 4 + q;
        if (row < NN) {
            float dv = dinv[row];
#pragma unroll
            for (int c = 0; c < 8; c++) {
                Gout[row * HID + c * 16 + l15] = f2b(acc[c][q] * dv);
            }
        }
    }
}

// ---------------- aggregation: one wave per node, lane owns 2 features ----------------
// One u32 load per lane per row (64 lanes x 4B = full 256B row, coalesced).
// 16 independent rows in flight in the main block; 4-block + masked-4 tail.
template<int LAYER>
__global__ __launch_bounds__(256) void k_agg(const u16* __restrict__ g,
                                             const int* __restrict__ rp,
                                             const int* __restrict__ col,
                                             const float* __restrict__ dinv,
                                             const float* __restrict__ bias,
                                             u16* __restrict__ tout,
                                             const int* __restrict__ batch,
                                             float* __restrict__ psum) {
    int w = threadIdx.x >> 6, l = threadIdx.x & 63;
    int v = blockIdx.x * 4 + w;
    if (v >= NN) return;
    int f0 = 2 * l;
    const u16* gl = g + f0;   // this lane's 4B column within any row

    // self loop: g[v]
    u32 u = *(const u32*)(gl + (size_t)v * HID);
    float a0 = blo(u), a1 = bhi(u);

    int e = rp[v], end = rp[v + 1];
    while (e < end) {
        int m = end - e; if (m > 64) m = 64;
        int ci = col[e + ((l < m) ? l : 0)];
        int j = 0;
        // full blocks of 16 — 16 loads in flight, no masks
        for (; j + 16 <= m; j += 16) {
            u32 uu[16];
#pragma unroll
            for (int k = 0; k < 16; k++) {
                int idx = __shfl(ci, j + k);
                uu[k] = *(const u32*)(gl + (size_t)idx * HID);
            }
#pragma unroll
            for (int k = 0; k < 16; k++) { a0 += blo(uu[k]); a1 += bhi(uu[k]); }
        }
        // full blocks of 4
        for (; j + 4 <= m; j += 4) {
            u32 uu[4];
#pragma unroll
            for (int k = 0; k < 4; k++) {
                int idx = __shfl(ci, j + k);
                uu[k] = *(const u32*)(gl + (size_t)idx * HID);
            }
#pragma unroll
            for (int k = 0; k < 4; k++) { a0 += blo(uu[k]); a1 += bhi(uu[k]); }
        }
        // masked tail (r = m-j in 1..3, wave-uniform masks -> SGPR)
        if (j < m) {
            int r = m - j;
            u32 uu[3];
#pragma unroll
            for (int k = 0; k < 3; k++) {
                int jk = j + k; int idx = __shfl(ci, (jk < m) ? jk : j);
                uu[k] = *(const u32*)(gl + (size_t)idx * HID);
            }
#pragma unroll
            for (int k = 0; k < 3; k++) {
                float mk = (k < r) ? 1.f : 0.f;
                a0 = fmaf(mk, blo(uu[k]), a0); a1 = fmaf(mk, bhi(uu[k]), a1);
            }
        }
        e += m;
    }

    float dv = dinv[v];
    float o0 = a0 * dv + bias[f0];
    float o1 = a1 * dv + bias[f0 + 1];
    if (LAYER == 1) {
        o0 = fmaxf(o0, 0.f); o1 = fmaxf(o1, 0.f);
        u32 outp = (u32)f2b(o0) | ((u32)f2b(o1) << 16);
        *(u32*)(tout + (size_t)v * HID + f0) = outp;
    } else {
        int bg = batch[v];
        atomicAdd(&psum[(size_t)bg * HID + f0],     o0);
        atomicAdd(&psum[(size_t)bg * HID + f0 + 1], o1);
    }
}

// ---------------- pooled FC ----------------
__global__ __launch_bounds__(64) void k_fc(const float* __restrict__ psum,
                                           const int* __restrict__ cntg,
                                           const float* __restrict__ Wfc,
                                           const float* __restrict__ bfc,
                                           float* __restrict__ out) {
    __shared__ float pooled[HID];
    int gph = blockIdx.x, t = threadIdx.x;
    float inv = 1.f / fmaxf((float)cntg[gph], 1.f);
    for (int k = t; k < HID; k += 64) pooled[k] = psum[gph * HID + k] * inv;
    __syncthreads();
    float acc = bfc[t];
    for (int k = 0; k < HID; k++) acc += pooled[k] * Wfc[k * NOUT + t];
    out[gph * NOUT + t] = acc;
}

extern "C" void kernel_launch(void* const* d_in, const int* in_sizes, int n_in,
                              void* d_out, int out_size, void* d_ws, size_t ws_size,
                              hipStream_t stream) {
    const float* x     = (const float*)d_in[0];
    const int*   ei    = (const int*)d_in[1];
    const int*   batch = (const int*)d_in[3];
    const float* W1    = (const float*)d_in[4];
    const float* b1    = (const float*)d_in[5];
    const float* W2    = (const float*)d_in[6];
    const float* b2    = (const float*)d_in[7];
    const float* Wfc   = (const float*)d_in[8];
    const float* bfc   = (const float*)d_in[9];
    float* out = (float*)d_out;

    const int* src = ei;
    const int* dst = ei + NE;

    char* p = (char*)d_ws;
    auto take = [&](size_t bytes) { char* r = p; p += (bytes + 255) & ~(size_t)255; return r; };
    int*   cnt  = (int*)take((size_t)NN * 4);
    int*   cur  = (int*)take((size_t)NN * 4);
    int*   rp   = (int*)take((size_t)(NN + 1) * 4);
    int*   bsum = (int*)take(256 * 4);
    int*   boff = (int*)take(256 * 4);
    float* dinv = (float*)take((size_t)NN * 4);
    int*   cntg = (int*)take((size_t)NG * 4);
    float* psum = (float*)take((size_t)NG * HID * 4);
    u16*   Wp1  = (u16*)take((size_t)32 * 64 * 8 * 2);
    u16*   Wp2  = (u16*)take((size_t)32 * 64 * 8 * 2);
    int*   col  = (int*)take((size_t)NE * 4);
    u16*   g    = (u16*)take((size_t)NN * HID * 2);
    u16*   t    = (u16*)take((size_t)NN * HID * 2);

    hipMemsetAsync(cnt,  0, (size_t)NN * 4, stream);
    hipMemsetAsync(cur,  0, (size_t)NN * 4, stream);
    hipMemsetAsync(cntg, 0, (size_t)NG * 4, stream);
    hipMemsetAsync(psum, 0, (size_t)NG * HID * 4, stream);

    k_hist <<<(NE + 255) / 256, 256, 0, stream>>>(dst, cnt);
    k_dinv <<<(NN + 255) / 256, 256, 0, stream>>>(cnt, batch, dinv, cntg);
    k_scan1<<<NB, 256, 0, stream>>>(cnt, rp, bsum);
    k_scan2<<<1, 128, 0, stream>>>(bsum, boff, rp + NN);
    k_scan3<<<(NN + 255) / 256, 256, 0, stream>>>(rp, boff);
    k_fill <<<(NE + 255) / 256, 256, 0, stream>>>(src, dst, rp, cur, col);
    k_pack <<<8, 256, 0, stream>>>(W1, Wp1);
    k_pack <<<8, 256, 0, stream>>>(W2, Wp2);

    k_gemm<1><<<(NN + 63) / 64, 256, 0, stream>>>((const void*)x, Wp1, dinv, g);
    k_agg<1> <<<(NN + 3) / 4, 256, 0, stream>>>(g, rp, col, dinv, b1, t, nullptr, nullptr);
    k_gemm<0><<<(NN + 63) / 64, 256, 0, stream>>>((const void*)t, Wp2, dinv, g);
    k_agg<2> <<<(NN + 3) / 4, 256, 0, stream>>>(g, rp, col, dinv, b2, nullptr, batch, psum);
    k_fc   <<<NG, 64, 0, stream>>>(psum, cntg, Wfc, bfc, out);
}